// Round 1
// baseline (836.155 us; speedup 1.0000x reference)
//
#include <hip/hip_runtime.h>

#define B_ 128
#define S_ 4096
#define D_ 256
#define U_ 128
#define SC_ 128
#define CH_ 32   // S_/SC_

typedef _Float16 half8 __attribute__((ext_vector_type(8)));
typedef _Float16 half4_t __attribute__((ext_vector_type(4)));
typedef float f32x4 __attribute__((ext_vector_type(4)));

// ---------------- setup kernels ----------------

__global__ void qp_kernel(const float* __restrict__ query,
                          const float* __restrict__ W1,
                          const float* __restrict__ b1,
                          const float* __restrict__ b2,
                          float* __restrict__ qp) {
  const int idx = blockIdx.x * 256 + threadIdx.x;   // 16384 = B_*U_
  const int b = idx >> 7;
  const int u = idx & 127;
  float acc = b1[u] + b2[u];              // fold b2 into qp
  const float* q = query + b * D_;
  #pragma unroll 8
  for (int d = 0; d < D_; ++d) acc += q[d] * W1[d * U_ + u];
  qp[idx] = acc;
}

__global__ void w2t_kernel(const float* __restrict__ W2,
                           _Float16* __restrict__ w2t) {
  const int idx = blockIdx.x * 256 + threadIdx.x;   // 32768 = U_*D_
  const int u = idx >> 8;
  const int d = idx & 255;
  w2t[idx] = (_Float16)W2[d * U_ + u];              // w2t[u][d]
}

// ---------------- main fused kernel ----------------

__global__ __launch_bounds__(256, 1)
void main_kernel(const float* __restrict__ values,
                 const float* __restrict__ qp,
                 const _Float16* __restrict__ w2t,
                 const float* __restrict__ Wv,
                 const float* __restrict__ bv,
                 float* __restrict__ scores,
                 float* __restrict__ part) {
  __shared__ _Float16 Alds[SC_][264];   // values tile, f16, padded pitch
  __shared__ _Float16 Blds[U_][264];    // W2^T, f16, padded pitch
  __shared__ float sb[2][SC_];
  __shared__ float score_sh[SC_];
  __shared__ float p_sh[SC_];
  __shared__ float qp_sh[U_];
  __shared__ float wv_sh[U_];
  __shared__ float ctxpart[8][D_];
  __shared__ float red[4];

  const int t = threadIdx.x;
  const int bid = blockIdx.x;
  const int b = bid >> 5;
  const int s0 = (bid & 31) * SC_;

  // ---- stage values tile [128 rows x 256 d] fp32 -> f16 LDS ----
  const f32x4* __restrict__ vsrc =
      (const f32x4*)(values + ((size_t)b * S_ + s0) * D_);
  #pragma unroll 8
  for (int i = 0; i < 32; ++i) {
    const int idx = t + i * 256;          // 0..8191
    const int row = idx >> 6;
    const int d4 = idx & 63;
    f32x4 v = vsrc[idx];
    half4_t h;
    h[0] = (_Float16)v[0]; h[1] = (_Float16)v[1];
    h[2] = (_Float16)v[2]; h[3] = (_Float16)v[3];
    *(half4_t*)&Alds[row][d4 * 4] = h;
  }
  // ---- stage W2^T (f16, already transposed in ws) ----
  const half8* __restrict__ wsrc = (const half8*)w2t;
  #pragma unroll 4
  for (int i = 0; i < 16; ++i) {
    const int idx = t + i * 256;          // 0..4095
    const int u = idx >> 5;
    const int d8 = idx & 31;
    *(half8*)&Blds[u][d8 * 8] = wsrc[idx];
  }
  if (t < U_) {
    qp_sh[t] = qp[b * U_ + t];
    wv_sh[t] = Wv[t];
  }
  __syncthreads();

  // ---- MFMA GEMM: vproj[128 rows][128 u], 4 waves, 64x64 tile/wave ----
  const int lane = t & 63;
  const int wave = t >> 6;
  const int wr = (wave >> 1) * 64;        // row base
  const int wcg = wave & 1;
  const int wc = wcg * 64;                // u base
  const int lm = lane & 15;
  const int lq = lane >> 4;
  const int lk = lq * 8;

  f32x4 acc[4][4];
  const f32x4 zero = {0.0f, 0.0f, 0.0f, 0.0f};
  #pragma unroll
  for (int mt = 0; mt < 4; ++mt)
    #pragma unroll
    for (int nt = 0; nt < 4; ++nt) acc[mt][nt] = zero;

  #pragma unroll
  for (int k = 0; k < 8; ++k) {
    const int kb = k * 32 + lk;
    half8 af[4], bf[4];
    #pragma unroll
    for (int mt = 0; mt < 4; ++mt)
      af[mt] = *(const half8*)&Alds[wr + mt * 16 + lm][kb];
    #pragma unroll
    for (int nt = 0; nt < 4; ++nt)
      bf[nt] = *(const half8*)&Blds[wc + nt * 16 + lm][kb];
    #pragma unroll
    for (int mt = 0; mt < 4; ++mt)
      #pragma unroll
      for (int nt = 0; nt < 4; ++nt)
        acc[mt][nt] = __builtin_amdgcn_mfma_f32_16x16x32_f16(
            af[mt], bf[nt], acc[mt][nt], 0, 0, 0);
  }

  // ---- epilogue: score[row] = sum_u tanh(vproj+qp)*Wv ----
  float qpv[4], wvv[4];
  #pragma unroll
  for (int nt = 0; nt < 4; ++nt) {
    const int u = wc + nt * 16 + lm;
    qpv[nt] = qp_sh[u];
    wvv[nt] = wv_sh[u];
  }
  #pragma unroll
  for (int mt = 0; mt < 4; ++mt) {
    float rs[4] = {0.0f, 0.0f, 0.0f, 0.0f};
    #pragma unroll
    for (int nt = 0; nt < 4; ++nt) {
      #pragma unroll
      for (int r = 0; r < 4; ++r) {
        const float x = acc[mt][nt][r] + qpv[nt];
        const float e = __expf(2.0f * x);
        const float th = 1.0f - 2.0f / (e + 1.0f);   // tanh(x)
        rs[r] += th * wvv[nt];
      }
    }
    #pragma unroll
    for (int r = 0; r < 4; ++r) {
      float v = rs[r];
      v += __shfl_xor(v, 1);
      v += __shfl_xor(v, 2);
      v += __shfl_xor(v, 4);
      v += __shfl_xor(v, 8);
      if (lm == 0) sb[wcg][wr + mt * 16 + lq * 4 + r] = v;
    }
  }
  __syncthreads();

  // ---- chunk-local softmax state ----
  if (t < SC_) {
    const float sc = sb[0][t] + sb[1][t] + bv[0];
    scores[(size_t)b * S_ + s0 + t] = sc;
    score_sh[t] = sc;
    float v = sc;
    v = fmaxf(v, __shfl_xor(v, 1));
    v = fmaxf(v, __shfl_xor(v, 2));
    v = fmaxf(v, __shfl_xor(v, 4));
    v = fmaxf(v, __shfl_xor(v, 8));
    v = fmaxf(v, __shfl_xor(v, 16));
    v = fmaxf(v, __shfl_xor(v, 32));
    if ((t & 63) == 0) red[t >> 6] = v;
  }
  __syncthreads();
  const float m_c = fmaxf(red[0], red[1]);
  if (t < SC_) {
    const float pv = __expf(score_sh[t] - m_c);
    p_sh[t] = pv;
    float v = pv;
    v += __shfl_xor(v, 1);
    v += __shfl_xor(v, 2);
    v += __shfl_xor(v, 4);
    v += __shfl_xor(v, 8);
    v += __shfl_xor(v, 16);
    v += __shfl_xor(v, 32);
    if ((t & 63) == 0) red[2 + (t >> 6)] = v;
  }
  __syncthreads();
  const float l_c = red[2] + red[3];

  // ---- context partial: ctx[v] = sum_row p[row]*values[row][v] (from LDS) ----
  float cacc[8];
  #pragma unroll
  for (int j = 0; j < 8; ++j) cacc[j] = 0.0f;
  const int v8 = (t & 31) * 8;
  const int rg = t >> 5;
  #pragma unroll
  for (int r = 0; r < 16; ++r) {
    const int row = rg * 16 + r;
    const float pr = p_sh[row];
    half8 hv = *(const half8*)&Alds[row][v8];
    #pragma unroll
    for (int j = 0; j < 8; ++j) cacc[j] += pr * (float)hv[j];
  }
  #pragma unroll
  for (int j = 0; j < 8; ++j) ctxpart[rg][v8 + j] = cacc[j];
  __syncthreads();
  {
    float s = 0.0f;
    #pragma unroll
    for (int g = 0; g < 8; ++g) s += ctxpart[g][t];
    const size_t base = (size_t)bid * 258;
    part[base + 2 + t] = s;
    if (t == 0) { part[base] = m_c; part[base + 1] = l_c; }
  }
}

// ---------------- combine partials -> context, final m/l ----------------

__global__ void combine_kernel(const float* __restrict__ part,
                               float* __restrict__ ml,
                               float* __restrict__ out_ctx) {
  const int b = blockIdx.x;
  const int t = threadIdx.x;   // 256 = D_
  float M = -1e30f;
  for (int c = 0; c < CH_; ++c)
    M = fmaxf(M, part[((size_t)(b * CH_ + c)) * 258]);
  float L = 0.0f, s = 0.0f;
  for (int c = 0; c < CH_; ++c) {
    const size_t base = ((size_t)(b * CH_ + c)) * 258;
    const float sc = __expf(part[base] - M);
    L += part[base + 1] * sc;
    s += part[base + 2 + t] * sc;
  }
  out_ctx[b * D_ + t] = s / L;
  if (t == 0) { ml[b * 2] = M; ml[b * 2 + 1] = L; }
}

// ---------------- attention weights output ----------------

__global__ void weights_kernel(const float* __restrict__ scores,
                               const float* __restrict__ ml,
                               float* __restrict__ out_w) {
  const int idx = blockIdx.x * 256 + threadIdx.x;   // 524288
  const int b = idx >> 12;
  const float M = ml[b * 2];
  const float L = ml[b * 2 + 1];
  out_w[idx] = __expf(scores[idx] - M) / L;
}

// ---------------- launch ----------------

extern "C" void kernel_launch(void* const* d_in, const int* in_sizes, int n_in,
                              void* d_out, int out_size, void* d_ws, size_t ws_size,
                              hipStream_t stream) {
  const float* query  = (const float*)d_in[0];
  const float* values = (const float*)d_in[1];
  const float* W1     = (const float*)d_in[2];
  const float* b1     = (const float*)d_in[3];
  const float* W2     = (const float*)d_in[4];
  const float* b2     = (const float*)d_in[5];
  const float* Wv     = (const float*)d_in[6];
  const float* bv     = (const float*)d_in[7];

  float* out_ctx = (float*)d_out;            // [128][256]
  float* out_w   = out_ctx + B_ * D_;        // [128][4096]

  char* ws = (char*)d_ws;
  float*     qp     = (float*)ws;                                  // 64 KB
  _Float16*  w2t    = (_Float16*)(ws + 65536);                     // 64 KB
  float*     scores = (float*)(ws + 131072);                       // 2 MB
  float*     part   = (float*)(ws + 131072 + 2097152);             // 128*32*258*4
  float*     ml     = (float*)(ws + 131072 + 2097152 + 4227072);   // 1 KB

  qp_kernel<<<dim3(64), dim3(256), 0, stream>>>(query, W1, b1, b2, qp);
  w2t_kernel<<<dim3(128), dim3(256), 0, stream>>>(W2, w2t);
  main_kernel<<<dim3(B_ * CH_), dim3(256), 0, stream>>>(values, qp, w2t, Wv, bv,
                                                        scores, part);
  combine_kernel<<<dim3(B_), dim3(256), 0, stream>>>(part, ml, out_ctx);
  weights_kernel<<<dim3(B_ * S_ / 256), dim3(256), 0, stream>>>(scores, ml, out_w);
}

// Round 2
// 729.617 us; speedup vs baseline: 1.1460x; 1.1460x over previous
//
#include <hip/hip_runtime.h>

#define B_ 128
#define S_ 4096
#define D_ 256
#define U_ 128
#define CR_ 64          // rows per chunk
#define NCH_ 32         // chunks per block (2048 rows / 64)
#define HALF_ROWS 2048
#define PITCH 264       // padded LDS pitch in halfs

typedef _Float16 half8 __attribute__((ext_vector_type(8)));
typedef _Float16 half4_t __attribute__((ext_vector_type(4)));
typedef float f32x4 __attribute__((ext_vector_type(4)));

// ---------------- setup kernels ----------------

__global__ void qp_kernel(const float* __restrict__ query,
                          const float* __restrict__ W1,
                          const float* __restrict__ b1,
                          const float* __restrict__ b2,
                          float* __restrict__ qp) {
  const int idx = blockIdx.x * 256 + threadIdx.x;   // 16384 = B_*U_
  const int b = idx >> 7;
  const int u = idx & 127;
  float acc = b1[u] + b2[u];              // fold b2 into qp
  const float* q = query + b * D_;
  #pragma unroll 8
  for (int d = 0; d < D_; ++d) acc += q[d] * W1[d * U_ + u];
  qp[idx] = acc;
}

__global__ void w2t_kernel(const float* __restrict__ W2,
                           _Float16* __restrict__ w2t) {
  const int idx = blockIdx.x * 256 + threadIdx.x;   // 32768 = U_*D_
  const int u = idx >> 8;
  const int d = idx & 255;
  w2t[idx] = (_Float16)W2[d * U_ + u];              // w2t[u][d]
}

// ---------------- main fused persistent kernel ----------------
// grid 256 blocks x 512 threads; block = (b, half): 32 chunks of 64 rows,
// online softmax + context accumulation, register prefetch of next chunk.

__global__ __launch_bounds__(512)
void main_kernel(const float* __restrict__ values,
                 const float* __restrict__ qp,
                 const _Float16* __restrict__ w2t,
                 const float* __restrict__ Wv,
                 const float* __restrict__ bv,
                 float* __restrict__ scores,
                 float* __restrict__ part) {
  __shared__ _Float16 Alds[CR_][PITCH];   // values chunk, f16
  __shared__ _Float16 Blds[U_][PITCH];    // W2^T
  __shared__ float sb[2][CR_];
  __shared__ float p_sh[CR_];
  __shared__ float qp_sh[U_];
  __shared__ float wv_sh[U_];
  __shared__ float ctxpart[16][D_];
  __shared__ float bc[4];                 // m_new, l_c, alpha, bv

  const int t = threadIdx.x;
  const int b = blockIdx.x >> 1;
  const int half = blockIdx.x & 1;
  const int lane = t & 63;
  const int wave = t >> 6;

  // ---- stage W2^T once ----
  const half8* __restrict__ wsrc = (const half8*)w2t;
  #pragma unroll
  for (int i = 0; i < 8; ++i) {
    const int idx = t + i * 512;          // 0..4095 h8
    const int u = idx >> 5;
    const int d8 = idx & 31;
    *(half8*)&Blds[u][d8 * 8] = wsrc[idx];
  }
  if (t < U_) { qp_sh[t] = qp[b * U_ + t]; wv_sh[t] = Wv[t]; }
  if (t == 0) bc[3] = bv[0];

  const f32x4* __restrict__ vbase =
      (const f32x4*)(values + ((size_t)b * S_ + half * HALF_ROWS) * D_);

  // ---- prologue: stage chunk 0 ----
  {
    f32x4 v[8];
    #pragma unroll
    for (int i = 0; i < 8; ++i) v[i] = vbase[t + i * 512];
    #pragma unroll
    for (int i = 0; i < 8; ++i) {
      const int idx = t + i * 512;        // 0..4095 f32x4
      const int row = idx >> 6;
      const int d4 = idx & 63;
      half4_t h;
      h[0] = (_Float16)v[i][0]; h[1] = (_Float16)v[i][1];
      h[2] = (_Float16)v[i][2]; h[3] = (_Float16)v[i][3];
      *(half4_t*)&Alds[row][d4 * 4] = h;
    }
  }
  __syncthreads();

  // per-wave GEMM tile: 16 rows x 64 u
  const int wr = (wave >> 1) * 16;
  const int wcg = wave & 1;
  const int wc = wcg * 64;
  const int lm = lane & 15;
  const int lq = lane >> 4;
  const int lk = lq * 8;

  float qpv[4], wvv[4];
  #pragma unroll
  for (int nt = 0; nt < 4; ++nt) {
    const int u = wc + nt * 16 + lm;
    qpv[nt] = qp_sh[u];
    wvv[nt] = wv_sh[u];
  }

  float M = -INFINITY, L = 0.0f;
  float cacc[8];
  #pragma unroll
  for (int j = 0; j < 8; ++j) cacc[j] = 0.0f;
  const int rg = t >> 5;                  // 0..15
  const int v8 = (t & 31) * 8;

  for (int c = 0; c < NCH_; ++c) {
    // ---- prefetch next chunk into registers (overlaps compute below) ----
    f32x4 pf[8];
    if (c + 1 < NCH_) {
      const f32x4* __restrict__ src = vbase + (size_t)(c + 1) * (CR_ * 64);
      #pragma unroll
      for (int i = 0; i < 8; ++i) pf[i] = src[t + i * 512];
    }

    // ---- GEMM: vproj for 64 rows x 128 u ----
    f32x4 acc[4];
    const f32x4 zero = {0.0f, 0.0f, 0.0f, 0.0f};
    #pragma unroll
    for (int nt = 0; nt < 4; ++nt) acc[nt] = zero;
    #pragma unroll
    for (int k = 0; k < 8; ++k) {
      const int kb = k * 32 + lk;
      half8 af = *(const half8*)&Alds[wr + lm][kb];
      #pragma unroll
      for (int nt = 0; nt < 4; ++nt) {
        half8 bf = *(const half8*)&Blds[wc + nt * 16 + lm][kb];
        acc[nt] = __builtin_amdgcn_mfma_f32_16x16x32_f16(af, bf, acc[nt], 0, 0, 0);
      }
    }

    // ---- epilogue: rows' partial scores ----
    float rs[4] = {0.0f, 0.0f, 0.0f, 0.0f};
    #pragma unroll
    for (int nt = 0; nt < 4; ++nt) {
      #pragma unroll
      for (int r = 0; r < 4; ++r) {
        const float x = acc[nt][r] + qpv[nt];
        const float e = __expf(2.0f * x);
        rs[r] += (1.0f - 2.0f / (e + 1.0f)) * wvv[nt];   // tanh(x)*wv
      }
    }
    #pragma unroll
    for (int r = 0; r < 4; ++r) {
      float v = rs[r];
      v += __shfl_xor(v, 1);
      v += __shfl_xor(v, 2);
      v += __shfl_xor(v, 4);
      v += __shfl_xor(v, 8);
      if (lm == 0) sb[wcg][wr + lq * 4 + r] = v;
    }
    __syncthreads();                       // S1: sb ready

    // ---- chunk softmax (wave 0) + online update ----
    if (t < CR_) {
      const float sc = sb[0][t] + sb[1][t] + bc[3];
      scores[(size_t)b * S_ + half * HALF_ROWS + c * CR_ + t] = sc;
      float mv = sc;
      mv = fmaxf(mv, __shfl_xor(mv, 1));
      mv = fmaxf(mv, __shfl_xor(mv, 2));
      mv = fmaxf(mv, __shfl_xor(mv, 4));
      mv = fmaxf(mv, __shfl_xor(mv, 8));
      mv = fmaxf(mv, __shfl_xor(mv, 16));
      mv = fmaxf(mv, __shfl_xor(mv, 32));
      const float m_new = fmaxf(M, mv);
      const float p = __expf(sc - m_new);
      p_sh[t] = p;
      float lv = p;
      lv += __shfl_xor(lv, 1);
      lv += __shfl_xor(lv, 2);
      lv += __shfl_xor(lv, 4);
      lv += __shfl_xor(lv, 8);
      lv += __shfl_xor(lv, 16);
      lv += __shfl_xor(lv, 32);
      if (t == 0) { bc[0] = m_new; bc[1] = lv; bc[2] = __expf(M - m_new); }
    }
    __syncthreads();                       // S2: p_sh, bc ready

    const float alpha = bc[2];
    const float l_c = bc[1];
    M = bc[0];
    L = L * alpha + l_c;

    // ---- context accumulate from LDS chunk ----
    #pragma unroll
    for (int j = 0; j < 8; ++j) cacc[j] *= alpha;
    #pragma unroll
    for (int r = 0; r < 4; ++r) {
      const int row = rg * 4 + r;
      const float pr = p_sh[row];
      half8 hv = *(const half8*)&Alds[row][v8];
      #pragma unroll
      for (int j = 0; j < 8; ++j) cacc[j] += pr * (float)hv[j];
    }
    __syncthreads();                       // S3: done reading Alds/p_sh/bc

    // ---- convert prefetched regs -> LDS for next chunk ----
    if (c + 1 < NCH_) {
      #pragma unroll
      for (int i = 0; i < 8; ++i) {
        const int idx = t + i * 512;
        const int row = idx >> 6;
        const int d4 = idx & 63;
        half4_t h;
        h[0] = (_Float16)pf[i][0]; h[1] = (_Float16)pf[i][1];
        h[2] = (_Float16)pf[i][2]; h[3] = (_Float16)pf[i][3];
        *(half4_t*)&Alds[row][d4 * 4] = h;
      }
    }
    __syncthreads();                       // S4: Alds ready
  }

  // ---- block epilogue: reduce context partials, write part ----
  #pragma unroll
  for (int j = 0; j < 8; ++j) ctxpart[rg][v8 + j] = cacc[j];
  __syncthreads();
  if (t < D_) {
    float s = 0.0f;
    #pragma unroll
    for (int g = 0; g < 16; ++g) s += ctxpart[g][t];
    const size_t base = (size_t)blockIdx.x * 258;
    part[base + 2 + t] = s;
    if (t == 0) { part[base] = M; part[base + 1] = L; }
  }
}

// ---------------- combine 2 halves -> context, final m/l ----------------

__global__ void combine_kernel(const float* __restrict__ part,
                               float* __restrict__ ml,
                               float* __restrict__ out_ctx) {
  const int b = blockIdx.x;
  const int t = threadIdx.x;   // 256 = D_
  const size_t b0 = (size_t)(b * 2) * 258;
  const size_t b1 = b0 + 258;
  const float m0 = part[b0], l0 = part[b0 + 1];
  const float m1 = part[b1], l1 = part[b1 + 1];
  const float Mf = fmaxf(m0, m1);
  const float s0 = __expf(m0 - Mf);
  const float s1 = __expf(m1 - Mf);
  const float Lf = l0 * s0 + l1 * s1;
  out_ctx[b * D_ + t] = (part[b0 + 2 + t] * s0 + part[b1 + 2 + t] * s1) / Lf;
  if (t == 0) { ml[b * 2] = Mf; ml[b * 2 + 1] = Lf; }
}

// ---------------- attention weights output ----------------

__global__ void weights_kernel(const float* __restrict__ scores,
                               const float* __restrict__ ml,
                               float* __restrict__ out_w) {
  const int idx = blockIdx.x * 256 + threadIdx.x;   // 524288
  const int b = idx >> 12;
  const float M = ml[b * 2];
  const float L = ml[b * 2 + 1];
  out_w[idx] = __expf(scores[idx] - M) / L;
}

// ---------------- launch ----------------

extern "C" void kernel_launch(void* const* d_in, const int* in_sizes, int n_in,
                              void* d_out, int out_size, void* d_ws, size_t ws_size,
                              hipStream_t stream) {
  const float* query  = (const float*)d_in[0];
  const float* values = (const float*)d_in[1];
  const float* W1     = (const float*)d_in[2];
  const float* b1     = (const float*)d_in[3];
  const float* W2     = (const float*)d_in[4];
  const float* b2     = (const float*)d_in[5];
  const float* Wv     = (const float*)d_in[6];
  const float* bv     = (const float*)d_in[7];

  float* out_ctx = (float*)d_out;            // [128][256]
  float* out_w   = out_ctx + B_ * D_;        // [128][4096]

  char* ws = (char*)d_ws;
  float*     qp     = (float*)ws;                                  // 64 KB
  _Float16*  w2t    = (_Float16*)(ws + 65536);                     // 64 KB
  float*     scores = (float*)(ws + 131072);                       // 2 MB
  float*     part   = (float*)(ws + 131072 + 2097152);             // 256*258*4 = 264 KB
  float*     ml     = (float*)(ws + 131072 + 2097152 + 264192);    // 1 KB

  qp_kernel<<<dim3(64), dim3(256), 0, stream>>>(query, W1, b1, b2, qp);
  w2t_kernel<<<dim3(128), dim3(256), 0, stream>>>(W2, w2t);
  main_kernel<<<dim3(B_ * 2), dim3(512), 0, stream>>>(values, qp, w2t, Wv, bv,
                                                      scores, part);
  combine_kernel<<<dim3(B_), dim3(256), 0, stream>>>(part, ml, out_ctx);
  weights_kernel<<<dim3(B_ * S_ / 256), dim3(256), 0, stream>>>(scores, ml, out_w);
}